// Round 10
// baseline (274.347 us; speedup 1.0000x reference)
//
#include <hip/hip_runtime.h>
#include <hip/hip_bf16.h>
#include <cstdint>

// LSTM cell, B=16384, IN=512, H=512, fused 4-gate bf16 MFMA GEMM.
// Round 9b: round 9 with the inline-asm operand fix (ext_vector u32x4 for
// ds_write_b128 payloads instead of HIP struct uint4).
// conv_a fused into GEMM (reg-stage f32 x/h -> bf16 -> ds_write), r7 geometry
// (256x128 tile, 2 blocks/CU, 4 waves/SIMD), XCD mapping grouping the 16
// A-panel sharers on one XCD. B keeps its tiny prepass + DMA.

typedef __attribute__((ext_vector_type(8))) __bf16 bf16x8;
typedef __attribute__((ext_vector_type(4))) float f32x4;
typedef __attribute__((ext_vector_type(4))) unsigned int u32x4;
typedef __attribute__((address_space(3))) char lds_char;

#define GLOAD_LDS16(gp, lp)                                                        \
    __builtin_amdgcn_global_load_lds(                                              \
        (const __attribute__((address_space(1))) void*)(gp),                       \
        (__attribute__((address_space(3))) void*)(lp), 16, 0, 0)

#define BAR()  asm volatile("s_barrier" ::: "memory")
#define VMW0() asm volatile("s_waitcnt vmcnt(0)" ::: "memory")
#define LGK0() { asm volatile("s_waitcnt lgkmcnt(0)" ::: "memory");                \
                 __builtin_amdgcn_sched_barrier(0); }
#define DSR(dst, off)                                                              \
    asm volatile("ds_read_b128 %0, %1" : "=v"(dst) : "v"(lds3 + (off)))
#define DSW(off, val)                                                              \
    asm volatile("ds_write_b128 %0, %1" :: "v"(lds3 + (off)), "v"(val))

__device__ __forceinline__ unsigned short f2bf(float f) {
    unsigned int u = __float_as_uint(f);
    u = (u + 0x7FFFu + ((u >> 16) & 1u)) >> 16;   // RNE
    return (unsigned short)u;
}
__device__ __forceinline__ unsigned int pk2(float a, float b) {
    return (unsigned)f2bf(a) | ((unsigned)f2bf(b) << 16);
}
__device__ __forceinline__ float tanh_fast(float x) {
    float ax = fabsf(x);
    float e  = __expf(2.f * ax);
    float t  = 1.f - 2.f / (e + 1.f);
    return copysignf(t, x);
}

// ---------------- prepass B (r7 layout, verified) ----------------
// B_pre: [nb=16][t=32] 8KB slices. chunk p (0..511): col = p>>2 (0..127),
// kc = (p&3) ^ ((col>>1)&3); col = g*32 + h_local; n = nb*32 + h_local;
// value = bf16(W_g[t*32 + kc*8 + u][n]), u=0..7.
__global__ __launch_bounds__(256) void conv_w_kernel(const float* __restrict__ w0,
                                                     const float* __restrict__ w1,
                                                     const float* __restrict__ w2,
                                                     const float* __restrict__ w3,
                                                     unsigned short* __restrict__ Wt) {
    int G  = blockIdx.x * 256 + threadIdx.x;   // 262,144 chunks
    int b  = G >> 9;
    int p  = G & 511;
    int nb = b >> 5;
    int t  = b & 31;
    int col = p >> 2;
    int kc  = (p & 3) ^ ((col >> 1) & 3);
    int g   = col >> 5;
    int n   = nb * 32 + (col & 31);
    int k0  = t * 32 + kc * 8;
    const float* Wg = (g == 0) ? w0 : (g == 1) ? w1 : (g == 2) ? w2 : w3;
    unsigned short us[8];
    #pragma unroll
    for (int u = 0; u < 8; ++u) us[u] = f2bf(Wg[(size_t)(k0 + u) * 512 + n]);
    uint4 o;
    o.x = (unsigned)us[0] | ((unsigned)us[1] << 16);
    o.y = (unsigned)us[2] | ((unsigned)us[3] << 16);
    o.z = (unsigned)us[4] | ((unsigned)us[5] << 16);
    o.w = (unsigned)us[6] | ((unsigned)us[7] << 16);
    *reinterpret_cast<uint4*>(Wt + ((size_t)b * 512 + p) * 8) = o;
}

// ---------------- fused GEMM: in-kernel A conversion ----------------
// Block tile 256 rows x (4g x 32h). 8 waves: wm=wid>>1 (64-row group),
// wn=wid&1 (16-h half). LDS per buffer 24KB: A[16KB] + B[8KB], double-buffered.
// A LDS image == old conv_a slice: chunk q (16B): row=q>>2,
// kc=(q&3)^((row>>1)&3), data = [x|h][mt*256+row][t*32+kc*8 .. +8] as bf16.
__global__ __launch_bounds__(512, 4) void lstm_gemm8(
    const float* __restrict__ x, const float* __restrict__ h,
    const char* __restrict__ Bpre,
    const float* __restrict__ c_cur,
    const float* __restrict__ bi_p, const float* __restrict__ bf_p,
    const float* __restrict__ bo_p, const float* __restrict__ bc_p,
    float* __restrict__ h_out, float* __restrict__ c_out)
{
    extern __shared__ char smem[];
    lds_char* lds3 = (lds_char*)smem;
    const int tid  = threadIdx.x;
    const int lane = tid & 63;
    const int wid  = tid >> 6;
    const int wm   = wid >> 1;    // 0..3 (64-row group)
    const int wn   = wid & 1;     // 0..1 (16-h half)

    // XCD grouping: xcd = bid&7 gets mt in {xcd*8 .. xcd*8+7}; the 16 blocks
    // sharing an A panel (all nb) are adjacent in dispatch on one XCD.
    const int bid = blockIdx.x;               // 1024 blocks
    const int mt  = (bid & 7) * 8 + (bid >> 7);
    const int nb  = (bid >> 3) & 15;

    const int ar    = lane & 15;
    const int swz   = ((lane >> 4) ^ ((ar >> 1) & 3)) << 4;
    const int aoffb = ar * 64 + swz;
    const int boffb = 16384 + (wn * 16 + ar) * 64 + swz;
    const int swl   = wid * 1024;

    // A staging addressing (per thread, 2 chunks: q=tid and q=512+tid)
    const int kc  = (tid & 3) ^ ((tid >> 3) & 3);
    const int r1  = mt * 256 + (tid >> 2);         // chunk tid (rows 0..127)
    // chunk 512+tid is row r1+128, same kc. 128 rows * 512 f32 = 65536 floats.
    const float* xrow1 = x + (size_t)r1 * 512 + kc * 8;
    const float* hrow1 = h + (size_t)r1 * 512 + kc * 8;

    const char* BpreB = Bpre + (((size_t)nb * 32) << 13) + (size_t)tid * 16;

    f32x4 acc[4][4];
    #pragma unroll
    for (int g = 0; g < 4; ++g)
        #pragma unroll
        for (int m = 0; m < 4; ++m)
            acc[g][m] = (f32x4){0.f, 0.f, 0.f, 0.f};

    bf16x8 aFr[4], bFr[4];
    float4 La0, La1, Lb0, Lb1;

#define ALOAD(t) {                                                      \
        const float* s_ = ((t) < 16) ? (xrow1 + (t) * 32)               \
                                     : (hrow1 + ((t) - 16) * 32);       \
        La0 = *reinterpret_cast<const float4*>(s_);                     \
        La1 = *reinterpret_cast<const float4*>(s_ + 4);                 \
        Lb0 = *reinterpret_cast<const float4*>(s_ + 65536);             \
        Lb1 = *reinterpret_cast<const float4*>(s_ + 65540); }
#define AWRITE(bb) {                                                    \
        u32x4 o1, o2;                                                   \
        o1.x = pk2(La0.x, La0.y); o1.y = pk2(La0.z, La0.w);             \
        o1.z = pk2(La1.x, La1.y); o1.w = pk2(La1.z, La1.w);             \
        o2.x = pk2(Lb0.x, Lb0.y); o2.y = pk2(Lb0.z, Lb0.w);             \
        o2.z = pk2(Lb1.x, Lb1.y); o2.w = pk2(Lb1.z, Lb1.w);             \
        DSW((bb) + tid * 16, o1);                                       \
        DSW((bb) + 8192 + tid * 16, o2); }
#define BSTAGE(t, bb) GLOAD_LDS16(BpreB + (((size_t)(t)) << 13),        \
                                  smem + (bb) + 16384 + swl)
#define MM1(m, g) acc[g][m] = __builtin_amdgcn_mfma_f32_16x16x32_bf16(   \
                      aFr[m], bFr[g], acc[g][m], 0, 0, 0);

    // prologue: stage tile 0 into buf0
    ALOAD(0);
    BSTAGE(0, 0);
    VMW0();
    AWRITE(0);
    LGK0();
    BAR();

    #pragma unroll 1
    for (int j = 0; j < 32; ++j) {
        const int buf  = (j & 1) * 24576;
        const int nbuf = buf ^ 24576;

        // 1. fragment reads of tile j
        #pragma unroll
        for (int mi = 0; mi < 4; ++mi)
            DSR(aFr[mi], buf + wm * 4096 + mi * 1024 + aoffb);
        #pragma unroll
        for (int g = 0; g < 4; ++g)
            DSR(bFr[g], buf + g * 2048 + boffb);

        // 2. issue next-tile staging loads (hidden under MFMA phase)
        if (j < 31) {
            ALOAD(j + 1);
            BSTAGE(j + 1, nbuf);
        }

        // 3. compute tile j
        LGK0();
        __builtin_amdgcn_s_setprio(1);
        MM1(0, 0) MM1(0, 1) MM1(1, 0) MM1(1, 1)
        MM1(0, 2) MM1(0, 3) MM1(1, 2) MM1(1, 3)
        MM1(2, 0) MM1(2, 1) MM1(3, 0) MM1(3, 1)
        MM1(2, 2) MM1(2, 3) MM1(3, 2) MM1(3, 3)
        __builtin_amdgcn_s_setprio(0);

        // 4. finish staging into nbuf, sync
        if (j < 31) {
            VMW0();        // A reg-loads + B DMA done
            AWRITE(nbuf);
        }
        LGK0();
        BAR();
    }

    // fused LSTM epilogue (r7, verified): all 4 gates in-lane
    const int r4   = (lane >> 4) * 4;
    const int hcol = nb * 32 + wn * 16 + ar;
    const float bii = bi_p[hcol], bff = bf_p[hcol];
    const float boo = bo_p[hcol], bcc = bc_p[hcol];
    #pragma unroll
    for (int m = 0; m < 4; ++m) {
        const int rowb = mt * 256 + wm * 64 + m * 16 + r4;
        #pragma unroll
        for (int rr = 0; rr < 4; ++rr) {
            const size_t o = (size_t)(rowb + rr) * 512 + hcol;
            float gi = acc[0][m][rr] + bii;
            float gf = acc[1][m][rr] + bff;
            float go = acc[2][m][rr] + boo;
            float gc = acc[3][m][rr] + bcc;
            float is = 1.f / (1.f + __expf(-gi));
            float fs = 1.f / (1.f + __expf(-gf));
            float os = 1.f / (1.f + __expf(-go));
            float ct = tanh_fast(gc);
            float cn = fs * c_cur[o] + is * ct;
            h_out[o] = os * tanh_fast(cn);
            c_out[o] = cn;
        }
    }
#undef ALOAD
#undef AWRITE
#undef BSTAGE
#undef MM1
}

extern "C" void kernel_launch(void* const* d_in, const int* in_sizes, int n_in,
                              void* d_out, int out_size, void* d_ws, size_t ws_size,
                              hipStream_t stream) {
    const float* x   = (const float*)d_in[0];
    const float* h   = (const float*)d_in[1];
    const float* c   = (const float*)d_in[2];
    const float* W_i = (const float*)d_in[3];
    const float* b_i = (const float*)d_in[4];
    const float* W_f = (const float*)d_in[5];
    const float* b_f = (const float*)d_in[6];
    const float* W_o = (const float*)d_in[7];
    const float* b_o = (const float*)d_in[8];
    const float* W_c = (const float*)d_in[9];
    const float* b_c = (const float*)d_in[10];

    unsigned short* Bpre = (unsigned short*)d_ws;   // 4,194,304 B

    float* h_out = (float*)d_out;
    float* c_out = h_out + (size_t)16384 * 512;

    (void)hipFuncSetAttribute(reinterpret_cast<const void*>(lstm_gemm8),
                              hipFuncAttributeMaxDynamicSharedMemorySize, 49152);

    conv_w_kernel<<<1024, 256, 0, stream>>>(W_i, W_f, W_o, W_c, Bpre);
    lstm_gemm8<<<1024, 512, 49152, stream>>>(x, h, (const char*)Bpre,
                                             c, b_i, b_f, b_o, b_c, h_out, c_out);
}

// Round 11
// 105.423 us; speedup vs baseline: 2.6023x; 2.6023x over previous
//
#include <hip/hip_runtime.h>
#include <hip/hip_bf16.h>
#include <cstdint>

// LSTM cell, B=16384, IN=512, H=512, fused 4-gate bf16 MFMA GEMM.
// Round 11: r5 kernel (BK=32, 4-deep ring, vmcnt(8), 1 barrier/tile) with ONE
// change: XCD-grouped block mapping. Old mapping put nb ≡ XCD -> every XCD
// staged the full 33.5MB A panel set from L3 (8x re-fetch, 536MB staged at
// ~6.4 TB/s = the measured 84us wall). New mapping gives XCD k the mt range
// {8k..8k+7}; A panels are staged once into one XCD's L2 and the 8 nb-sharers
// hit L2. B (4MB) fits every L2.

typedef __attribute__((ext_vector_type(8))) __bf16 bf16x8;
typedef __attribute__((ext_vector_type(4))) float f32x4;
typedef __attribute__((address_space(3))) char lds_char;

#define GLOAD_LDS16(gp, lp)                                                        \
    __builtin_amdgcn_global_load_lds(                                              \
        (const __attribute__((address_space(1))) void*)(gp),                       \
        (__attribute__((address_space(3))) void*)(lp), 16, 0, 0)

#define BAR()  asm volatile("s_barrier" ::: "memory")
#define VMW8() asm volatile("s_waitcnt vmcnt(8)" ::: "memory")
#define VMW4() asm volatile("s_waitcnt vmcnt(4)" ::: "memory")
#define VMW0() asm volatile("s_waitcnt vmcnt(0)" ::: "memory")
#define LGK0() { asm volatile("s_waitcnt lgkmcnt(0)" ::: "memory");                \
                 __builtin_amdgcn_sched_barrier(0); }
#define DSR(dst, off)                                                              \
    asm volatile("ds_read_b128 %0, %1" : "=v"(dst) : "v"(lds3 + (off)))

__device__ __forceinline__ unsigned short f2bf(float f) {
    unsigned int u = __float_as_uint(f);
    u = (u + 0x7FFFu + ((u >> 16) & 1u)) >> 16;   // RNE
    return (unsigned short)u;
}
__device__ __forceinline__ float tanh_fast(float x) {
    float ax = fabsf(x);
    float e  = __expf(2.f * ax);
    float t  = 1.f - 2.f / (e + 1.f);
    return copysignf(t, x);
}

// ---------------- prepass A (r5, verified) ----------------
__global__ __launch_bounds__(256) void conv_a_kernel(const float* __restrict__ x,
                                                     const float* __restrict__ h,
                                                     unsigned short* __restrict__ A) {
    int G  = blockIdx.x * 256 + threadIdx.x;
    int b  = G >> 10;
    int p  = G & 1023;
    int mt = b >> 5;
    int kt = (b >> 1) & 15;
    int ks = b & 1;
    int row = p >> 2;
    int c   = (p & 3) ^ ((row >> 1) & 3);
    int r   = mt * 256 + row;
    int k0  = kt * 64 + ks * 32 + c * 8;
    const float* src = (k0 < 512) ? (x + (size_t)r * 512 + k0)
                                  : (h + (size_t)r * 512 + (k0 - 512));
    const float4* s4 = reinterpret_cast<const float4*>(src);
    float4 v0 = s4[0];
    float4 v1 = s4[1];
    uint4 o;
    o.x = (unsigned)f2bf(v0.x) | ((unsigned)f2bf(v0.y) << 16);
    o.y = (unsigned)f2bf(v0.z) | ((unsigned)f2bf(v0.w) << 16);
    o.z = (unsigned)f2bf(v1.x) | ((unsigned)f2bf(v1.y) << 16);
    o.w = (unsigned)f2bf(v1.z) | ((unsigned)f2bf(v1.w) << 16);
    *reinterpret_cast<uint4*>(A + ((size_t)b * 1024 + p) * 8) = o;
}

// ---------------- prepass B (r5, verified) ----------------
__global__ __launch_bounds__(256) void conv_w_kernel(const float* __restrict__ w0,
                                                     const float* __restrict__ w1,
                                                     const float* __restrict__ w2,
                                                     const float* __restrict__ w3,
                                                     unsigned short* __restrict__ Wt) {
    int G  = blockIdx.x * 256 + threadIdx.x;
    int b  = G >> 10;
    int p  = G & 1023;
    int nb = b >> 5;
    int kt = (b >> 1) & 15;
    int ks = b & 1;
    int col = p >> 2;
    int c   = (p & 3) ^ ((col >> 1) & 3);
    int g   = col >> 6;
    int hh  = col & 63;
    int n   = nb * 64 + hh;
    int k0  = kt * 64 + ks * 32 + c * 8;
    const float* Wg = (g == 0) ? w0 : (g == 1) ? w1 : (g == 2) ? w2 : w3;
    unsigned short us[8];
    #pragma unroll
    for (int u = 0; u < 8; ++u) us[u] = f2bf(Wg[(size_t)(k0 + u) * 512 + n]);
    uint4 o;
    o.x = (unsigned)us[0] | ((unsigned)us[1] << 16);
    o.y = (unsigned)us[2] | ((unsigned)us[3] << 16);
    o.z = (unsigned)us[4] | ((unsigned)us[5] << 16);
    o.w = (unsigned)us[6] | ((unsigned)us[7] << 16);
    *reinterpret_cast<uint4*>(Wt + ((size_t)b * 1024 + p) * 8) = o;
}

// ---------------- fused GEMM: r5 + XCD-grouped mapping ----------------
__global__ __launch_bounds__(512, 2) void lstm_gemm8(
    const char* __restrict__ Apre, const char* __restrict__ Bpre,
    const float* __restrict__ c_cur,
    const float* __restrict__ bi_p, const float* __restrict__ bf_p,
    const float* __restrict__ bo_p, const float* __restrict__ bc_p,
    float* __restrict__ h_out, float* __restrict__ c_out)
{
    extern __shared__ char smem[];
    lds_char* lds3 = (lds_char*)smem;
    const int tid  = threadIdx.x;
    const int lane = tid & 63;
    const int wid  = tid >> 6;
    const int wm   = wid >> 2;
    const int wn   = wid & 3;

    // XCD-grouped mapping (THE round-11 change): XCD k = bid&7 owns
    // mt in {8k..8k+7}; for fixed mt, the 8 nb-sharers are adjacent
    // dispatches on the same XCD -> A panel L2-resident, staged once.
    const int mt = (blockIdx.x & 7) * 8 + (blockIdx.x >> 6);
    const int nb = (blockIdx.x >> 3) & 7;

    const int ar    = lane & 15;
    const int swz   = ((lane >> 4) ^ ((ar >> 1) & 3)) << 4;
    const int aoffb = ar * 64 + swz;
    const int boffb = (wn * 16 + ar) * 64 + swz;
    const int swl   = wid * 1024;

    const char* ApreB = Apre + (((size_t)mt * 32) << 14) + (size_t)tid * 16;
    const char* BpreB = Bpre + (((size_t)nb * 32) << 14) + (size_t)tid * 16;

#define STAGE(t, bb) {                                                  \
        const char* ga_ = ApreB + (((size_t)(t)) << 14);                \
        const char* gb_ = BpreB + (((size_t)(t)) << 14);                \
        GLOAD_LDS16(ga_,        smem + (bb) + swl);                     \
        GLOAD_LDS16(ga_ + 8192, smem + (bb) + 8192 + swl);              \
        GLOAD_LDS16(gb_,        smem + (bb) + 16384 + swl);             \
        GLOAD_LDS16(gb_ + 8192, smem + (bb) + 16384 + 8192 + swl); }

    f32x4 acc[4][8];
    #pragma unroll
    for (int g = 0; g < 4; ++g)
        #pragma unroll
        for (int m = 0; m < 8; ++m)
            acc[g][m] = (f32x4){0.f, 0.f, 0.f, 0.f};

    bf16x8 aFr[8], bFr[4];

    // prologue: stage K-tiles 0,1,2 into ring bufs 0,1,2 (12 loads in flight)
    STAGE(0, 0);
    STAGE(1, 32768);
    STAGE(2, 65536);

    #pragma unroll 1
    for (int j = 0; j < 32; ++j) {
        const int buf  = (j & 3) << 15;
        const int bufN = ((j + 3) & 3) << 15;

        if (j < 30)      { VMW8(); }
        else if (j == 30){ VMW4(); }
        else             { VMW0(); }
        BAR();
        if (j < 29) STAGE(j + 3, bufN);

        #pragma unroll
        for (int mh = 0; mh < 2; ++mh)
            #pragma unroll
            for (int mi = 0; mi < 4; ++mi)
                DSR(aFr[mh * 4 + mi],
                    buf + wm * 8192 + mh * 4096 + mi * 1024 + aoffb);
        #pragma unroll
        for (int g = 0; g < 4; ++g)
            DSR(bFr[g], buf + 16384 + g * 4096 + boffb);

        LGK0();
        __builtin_amdgcn_s_setprio(1);
        #pragma unroll
        for (int g = 0; g < 4; ++g)
            #pragma unroll
            for (int m = 0; m < 8; ++m)
                acc[g][m] = __builtin_amdgcn_mfma_f32_16x16x32_bf16(
                    aFr[m], bFr[g], acc[g][m], 0, 0, 0);
        __builtin_amdgcn_s_setprio(0);
    }

    // fused LSTM epilogue: all 4 gates in-lane
    const int r4   = (lane >> 4) * 4;
    const int hcol = nb * 64 + wn * 16 + ar;
    const float bii = bi_p[hcol], bff = bf_p[hcol];
    const float boo = bo_p[hcol], bcc = bc_p[hcol];
    #pragma unroll
    for (int m = 0; m < 8; ++m) {
        const int rowb = mt * 256 + wm * 128 + m * 16 + r4;
        #pragma unroll
        for (int rr = 0; rr < 4; ++rr) {
            const size_t o = (size_t)(rowb + rr) * 512 + hcol;
            float gi = acc[0][m][rr] + bii;
            float gf = acc[1][m][rr] + bff;
            float go = acc[2][m][rr] + boo;
            float gc = acc[3][m][rr] + bcc;
            float is = 1.f / (1.f + __expf(-gi));
            float fs = 1.f / (1.f + __expf(-gf));
            float os = 1.f / (1.f + __expf(-go));
            float ct = tanh_fast(gc);
            float cn = fs * c_cur[o] + is * ct;
            h_out[o] = os * tanh_fast(cn);
            c_out[o] = cn;
        }
    }
#undef STAGE
}

extern "C" void kernel_launch(void* const* d_in, const int* in_sizes, int n_in,
                              void* d_out, int out_size, void* d_ws, size_t ws_size,
                              hipStream_t stream) {
    const float* x   = (const float*)d_in[0];
    const float* h   = (const float*)d_in[1];
    const float* c   = (const float*)d_in[2];
    const float* W_i = (const float*)d_in[3];
    const float* b_i = (const float*)d_in[4];
    const float* W_f = (const float*)d_in[5];
    const float* b_f = (const float*)d_in[6];
    const float* W_o = (const float*)d_in[7];
    const float* b_o = (const float*)d_in[8];
    const float* W_c = (const float*)d_in[9];
    const float* b_c = (const float*)d_in[10];

    unsigned short* Apre = (unsigned short*)d_ws;
    unsigned short* Bpre = (unsigned short*)((char*)d_ws + 33554432);

    float* h_out = (float*)d_out;
    float* c_out = h_out + (size_t)16384 * 512;

    (void)hipFuncSetAttribute(reinterpret_cast<const void*>(lstm_gemm8),
                              hipFuncAttributeMaxDynamicSharedMemorySize, 131072);

    conv_a_kernel<<<8192, 256, 0, stream>>>(x, h, Apre);
    conv_w_kernel<<<1024, 256, 0, stream>>>(W_i, W_f, W_o, W_c, Bpre);
    lstm_gemm8<<<512, 512, 131072, stream>>>((const char*)Apre, (const char*)Bpre,
                                             c, b_i, b_f, b_o, b_c, h_out, c_out);
}